// Round 8
// baseline (352.664 us; speedup 1.0000x reference)
//
#include <hip/hip_runtime.h>
#include <hip/hip_bf16.h>
#include <stdint.h>

// ---------- types ----------
typedef __attribute__((ext_vector_type(8))) __bf16 bf16x8;
typedef __attribute__((ext_vector_type(4))) float f32x4;
typedef __attribute__((ext_vector_type(8))) unsigned short ushort8;

typedef const void __attribute__((address_space(1))) gv_t;
typedef void __attribute__((address_space(3))) lv_t;

#define GL16(g, l) __builtin_amdgcn_global_load_lds((gv_t*)(g), (lv_t*)(l), 16, 0, 0)

__device__ __forceinline__ unsigned short f2bf(float f) {
    unsigned int u = __float_as_uint(f);
    u += 0x7fffu + ((u >> 16) & 1u);
    return (unsigned short)(u >> 16);
}

// ---------- kernel 1: per-group int4 quant-dequant of W -> bf16 bits ----------
__global__ void __launch_bounds__(256) qdq_weight(const float* __restrict__ w,
                                                  unsigned short* __restrict__ wb,
                                                  int n_groups) {
    int g = blockIdx.x * 256 + threadIdx.x;
    if (g >= n_groups) return;
    const float4* p = (const float4*)w + (size_t)g * 2;
    float4 v0 = p[0], v1 = p[1];
    float t[8] = {v0.x, v0.y, v0.z, v0.w, v1.x, v1.y, v1.z, v1.w};
    float amax = 0.0f;
#pragma unroll
    for (int j = 0; j < 8; ++j) amax = fmaxf(amax, fabsf(t[j]));
    float scale = fmaxf(amax / 7.0f, 1e-8f);
    ushort8 o;
#pragma unroll
    for (int j = 0; j < 8; ++j) {
        float q = rintf(t[j] / scale);
        q = fminf(fmaxf(q, -7.0f), 7.0f);
        o[j] = f2bf(q * scale);
    }
    *((ushort8*)wb + g) = o;
}

// ---------- kernel 2: f32 -> bf16 cast of x ----------
__global__ void __launch_bounds__(256) cvt_bf16(const float* __restrict__ x,
                                                unsigned short* __restrict__ xb,
                                                int n8) {
    int i = blockIdx.x * 256 + threadIdx.x;
    if (i >= n8) return;
    const float4* p = (const float4*)x + (size_t)i * 2;
    float4 v0 = p[0], v1 = p[1];
    ushort8 o;
    o[0] = f2bf(v0.x); o[1] = f2bf(v0.y); o[2] = f2bf(v0.z); o[3] = f2bf(v0.w);
    o[4] = f2bf(v1.x); o[5] = f2bf(v1.y); o[6] = f2bf(v1.z); o[7] = f2bf(v1.w);
    *((ushort8*)xb + i) = o;
}

// ---------- kernel 3: 256x256 "big-wave" GEMM: 4 waves, each 128x128 ----------
// Rationale: LDS read traffic per FLOP ~ (1/Wm + 1/Wn). 128x128 wave tiles cut
// read bytes 33% vs 128x64, moving the LDS port off the critical path.
// 1 wave/SIMD: ds_read/MFMA interleave is in-wave ILP (compiler-scheduled),
// no block-wide lockstep partner to starve. One barrier + one vmcnt(0)/K-tile,
// both issued ~2000 cyc ahead of the wait -> essentially free.
#define BM 256
#define BN 256
#define BK 64

#define BAR_()   asm volatile("s_barrier" ::: "memory")
#define VM0_()   asm volatile("s_waitcnt vmcnt(0)" ::: "memory")

// stage one 256x64 operand tile into buf b: 8 rounds x 1 GL16 per thread
#define STAGE_T(sdst, gsrc, b, kk)                                             \
    {                                                                          \
        _Pragma("unroll")                                                      \
        for (int rr = 0; rr < 8; ++rr)                                         \
            GL16(gsrc + (size_t)(rr * 32 + srow) * K + (kk) + schunk,          \
                 &sdst[b][(rr * 32 + w * 8) * BK]);                            \
    }

__global__ void __launch_bounds__(256, 1)
gemmBW(const unsigned short* __restrict__ A,   // [M][K] bf16 bits (x)
       const unsigned short* __restrict__ B,   // [N][K] bf16 bits (w_deq)
       const float* __restrict__ bias,
       float* __restrict__ C,
       int M, int N, int K) {
    __shared__ unsigned short sA[2][BM * BK];   // 2 x 32 KB
    __shared__ unsigned short sB[2][BN * BK];   // 2 x 32 KB  (128 KiB)

    const int t  = threadIdx.x;
    const int w  = t >> 6;        // wave 0..3
    const int ln = t & 63;
    const int lr = ln & 15;
    const int lk = ln >> 4;
    const int wr = w >> 1;        // wave M index (128 rows)
    const int wc = w & 1;         // wave N index (128 cols)

    // T1: bijective XCD swizzle (gridDim.x = 512, % 8 == 0)
    const int nbn = N / BN;
    const int bid = blockIdx.x;
    const int swz = ((int)gridDim.x & 7) ? bid
                  : ((bid & 7) * ((int)gridDim.x >> 3) + (bid >> 3));
    const int m0 = (swz / nbn) * BM;
    const int n0 = (swz % nbn) * BN;

    const unsigned short* gA = A + (size_t)m0 * K;
    const unsigned short* gB = B + (size_t)n0 * K;

    // staging coords: 256 threads cover 32 rows x 8 chunks per round;
    // global source chunk pre-swizzled (chunk ^= row&7), LDS linear (rule #21)
    const int srow   = t >> 3;                            // 0..31
    const int schunk = (((t & 7) ^ (srow & 7)) << 3);     // elements

    // swizzled ds_read element offsets (proven 0-conflict in rounds 2-6)
    const int sw = (lr & 7) << 3;
    const int e0 = (lk * 8) ^ sw;
    const int e1 = (32 + lk * 8) ^ sw;

    f32x4 acc[8][8];
#pragma unroll
    for (int i = 0; i < 8; ++i)
#pragma unroll
        for (int j = 0; j < 8; ++j)
            acc[i][j] = (f32x4)(0.0f);

    const int NT = K / BK;   // 64

    // prologue: tile 0 -> buf 0
    STAGE_T(sA, gA, 0, 0);
    STAGE_T(sB, gB, 0, 0);
    VM0_();
    BAR_();

    for (int tt = 0; tt < NT; ++tt) {
        const int cur = tt & 1;
        const int nxt = cur ^ 1;

        // stage next tile first (vm queue fills while we compute)
        if (tt + 1 < NT) {
            const int kk = (tt + 1) * BK;
            STAGE_T(sA, gA, nxt, kk);
            STAGE_T(sB, gB, nxt, kk);
        }

        // A fragments: hold all 8 m-frags x 2 k-steps (64 VGPR)
        bf16x8 af[8][2];
#pragma unroll
        for (int mi = 0; mi < 8; ++mi) {
            const int s_ = (wr * 128 + mi * 16 + lr) * BK;
            af[mi][0] = *(const bf16x8*)&sA[cur][s_ + e0];
            af[mi][1] = *(const bf16x8*)&sA[cur][s_ + e1];
        }

        // stream B fragments per-ni; compiler interleaves ds_read with MFMA
#pragma unroll
        for (int ni = 0; ni < 8; ++ni) {
            const int s_ = (wc * 128 + ni * 16 + lr) * BK;
            bf16x8 b0 = *(const bf16x8*)&sB[cur][s_ + e0];
            bf16x8 b1 = *(const bf16x8*)&sB[cur][s_ + e1];
#pragma unroll
            for (int mi = 0; mi < 8; ++mi) {
                acc[mi][ni] = __builtin_amdgcn_mfma_f32_16x16x32_bf16(
                    af[mi][0], b0, acc[mi][ni], 0, 0, 0);
                acc[mi][ni] = __builtin_amdgcn_mfma_f32_16x16x32_bf16(
                    af[mi][1], b1, acc[mi][ni], 0, 0, 0);
            }
        }

        VM0_();   // next tile landed (issued ~2000 cyc ago)
        BAR_();   // all waves done reading cur; next iter may overwrite
    }

    // epilogue: C/D layout col = lane&15, row = (lane>>4)*4 + reg
#pragma unroll
    for (int ni = 0; ni < 8; ++ni) {
        const int n = n0 + wc * 128 + ni * 16 + lr;
        const float bv = bias[n];
#pragma unroll
        for (int mi = 0; mi < 8; ++mi) {
            const int m = m0 + wr * 128 + mi * 16 + lk * 4;
            f32x4 v = acc[mi][ni];
            C[(size_t)(m + 0) * N + n] = v[0] + bv;
            C[(size_t)(m + 1) * N + n] = v[1] + bv;
            C[(size_t)(m + 2) * N + n] = v[2] + bv;
            C[(size_t)(m + 3) * N + n] = v[3] + bv;
        }
    }
}

// ---------- launcher ----------
extern "C" void kernel_launch(void* const* d_in, const int* in_sizes, int n_in,
                              void* d_out, int out_size, void* d_ws, size_t ws_size,
                              hipStream_t stream) {
    const float* x    = (const float*)d_in[0];
    const float* wgt  = (const float*)d_in[1];
    const float* bias = (const float*)d_in[2];
    float* out        = (float*)d_out;

    const int dout = in_sizes[2];            // 4096
    const int din  = in_sizes[1] / dout;     // 4096
    const int M    = in_sizes[0] / din;      // 8192
    const int N    = dout, K = din;

    unsigned short* xb = (unsigned short*)d_ws;          // [M][K] bf16 bits
    unsigned short* wb = xb + (size_t)M * K;             // [N][K] bf16 bits

    const int ng_w = (N * K) / 8;
    qdq_weight<<<(ng_w + 255) / 256, 256, 0, stream>>>(wgt, wb, ng_w);

    const int n8_x = (M * K) / 8;
    cvt_bf16<<<(n8_x + 255) / 256, 256, 0, stream>>>(x, xb, n8_x);

    const int nwg = (M / BM) * (N / BN);     // 32 * 16 = 512, % 8 == 0
    gemmBW<<<nwg, 256, 0, stream>>>(xb, wb, bias, out, M, N, K);
}